// Round 7
// baseline (28.060 us; speedup 1.0000x reference)
//
#include <hip/hip_runtime.h>
#include <cstdint>
#include <cmath>

#define N_WIRES 10
#define N_OPS 30
#define NG_FAST 40   // 30 random + 10 fused(RY*RX)
#define NG_SAFE 50   // 30 random + 10x(RX,RY) separate (R3-proven tail)
#define NG_MAX 50

typedef __attribute__((ext_vector_type(2))) float f2;   // (re, im) packed pair

// ---------------- compile-time numpy RandomState(42) replication -------------

struct CERng { uint32_t mt[624]; int mti; };

constexpr uint32_t ce_next32(CERng& r) {
  if (r.mti >= 624) {
    for (int i = 0; i < 624; ++i) {
      uint32_t y = (r.mt[i] & 0x80000000u) | (r.mt[(i + 1) % 624] & 0x7fffffffu);
      uint32_t v = r.mt[(i + 397) % 624] ^ (y >> 1);
      if (y & 1u) v ^= 2567483615u;
      r.mt[i] = v;
    }
    r.mti = 0;
  }
  uint32_t y = r.mt[r.mti++];
  y ^= y >> 11;
  y ^= (y << 7) & 2636928640u;
  y ^= (y << 15) & 4022730752u;
  y ^= y >> 18;
  return y;
}

constexpr uint32_t ce_masked(CERng& r, uint32_t rng) {  // legacy single-32b draw (R2-validated)
  if (rng == 0) return 0;
  uint32_t mask = rng;
  mask |= mask >> 1; mask |= mask >> 2; mask |= mask >> 4;
  mask |= mask >> 8; mask |= mask >> 16;
  uint32_t v = ce_next32(r) & mask;
  while (v > rng) v = ce_next32(r) & mask;
  return v;
}

// type: 0=rx 1=ry 2=rz 3=cnot 4=fused(RY*RX).  p0/p1 are BIT positions after remap.
struct Full { int n; int type[NG_MAX]; int p0[NG_MAX]; int p1[NG_MAX]; int aidx[NG_MAX]; int wbit[N_WIRES]; };

constexpr Full make_full(bool fused) {
  Full f{};
  int rty[N_OPS] = {}, rw0[N_OPS] = {}, rw1[N_OPS] = {};
  CERng r{};
  r.mt[0] = 42u;
  for (int i = 1; i < 624; ++i)
    r.mt[i] = 1812433253u * (r.mt[i - 1] ^ (r.mt[i - 1] >> 30)) + (uint32_t)i;
  r.mti = 624;
  for (int k = 0; k < N_OPS; ++k) {
    int g = (int)ce_masked(r, 3u);
    if (g == 3) {
      int arr[N_WIRES] = {0,1,2,3,4,5,6,7,8,9};
      for (int i = N_WIRES - 1; i >= 1; --i) {
        int j = (int)ce_masked(r, (uint32_t)i);
        int t = arr[i]; arr[i] = arr[j]; arr[j] = t;
      }
      rty[k] = 3; rw0[k] = arr[0]; rw1[k] = arr[1];
    } else {
      rty[k] = g; rw0[k] = (int)ce_masked(r, 9u); rw1[k] = -1;
    }
  }
  int cost[N_WIRES] = {};
  for (int k = 0; k < N_OPS; ++k) {
    if (rty[k] == 3) { cost[rw0[k]] += 1; cost[rw1[k]] += 2; }
    else if (rty[k] != 2) cost[rw0[k]] += 2;
  }
  for (int w = 0; w < N_WIRES; ++w) cost[w] += 2;
  int ord[N_WIRES] = {0,1,2,3,4,5,6,7,8,9};
  for (int i = 0; i < N_WIRES; ++i) {
    int best = i;
    for (int j = i + 1; j < N_WIRES; ++j)
      if (cost[ord[j]] > cost[ord[best]]) best = j;
    int t = ord[i]; ord[i] = ord[best]; ord[best] = t;
  }
  // hottest 4 -> register bits; lane bits: bit4/5=DPP 1-op (mask1/2),
  // bit8/9=permlane swap (mask16/32), bit6/7=DPP 2-op composition (mask4/8)
  f.wbit[ord[0]] = 3; f.wbit[ord[1]] = 2; f.wbit[ord[2]] = 1; f.wbit[ord[3]] = 0;
  f.wbit[ord[4]] = 4; f.wbit[ord[5]] = 5;
  f.wbit[ord[6]] = 8; f.wbit[ord[7]] = 9;
  f.wbit[ord[8]] = 6; f.wbit[ord[9]] = 7;
  for (int k = 0; k < N_OPS; ++k) {
    f.type[k] = rty[k];
    if (rty[k] == 3) { f.p0[k] = f.wbit[rw0[k]]; f.p1[k] = f.wbit[rw1[k]]; f.aidx[k] = 0; }
    else             { f.p0[k] = f.wbit[rw0[k]]; f.p1[k] = 0; f.aidx[k] = 10 + k; }
  }
  if (fused) {
    f.n = NG_FAST;
    for (int w = 0; w < N_WIRES; ++w) {
      f.type[N_OPS + w] = 4; f.p0[N_OPS + w] = f.wbit[w]; f.p1[N_OPS + w] = 0; f.aidx[N_OPS + w] = 0;
    }
  } else {
    f.n = NG_SAFE;
    for (int w = 0; w < N_WIRES; ++w) {
      f.type[N_OPS + 2*w]     = 0; f.p0[N_OPS + 2*w]     = f.wbit[w]; f.p1[N_OPS + 2*w]     = 0; f.aidx[N_OPS + 2*w]     = 40;
      f.type[N_OPS + 2*w + 1] = 1; f.p0[N_OPS + 2*w + 1] = f.wbit[w]; f.p1[N_OPS + 2*w + 1] = 0; f.aidx[N_OPS + 2*w + 1] = 41;
    }
  }
  return f;
}

constexpr Full FULLF = make_full(true);
constexpr Full FULLS = make_full(false);

constexpr int wire_at_bit(int bp) {
  for (int w = 0; w < N_WIRES; ++w) if (FULLF.wbit[w] == bp) return w;
  return 0;
}
constexpr int RW0 = wire_at_bit(0), RW1 = wire_at_bit(1), RW2 = wire_at_bit(2), RW3 = wire_at_bit(3);
constexpr int LW0 = wire_at_bit(4), LW1 = wire_at_bit(5), LW2 = wire_at_bit(6),
              LW3 = wire_at_bit(7), LW4 = wire_at_bit(8), LW5 = wire_at_bit(9);

// --------------------------------- device ------------------------------------

struct U2v { f2 u00, u01, u10, u11; };   // complex entries as (re, im)
struct Ctx { int lane; bool s16, s32; }; // s16/s32: precomputed permlane result selects

__device__ inline f2 fswap(f2 v) { return __builtin_shufflevector(v, v, 1, 0); }

// complex multiply-accumulate: acc + u*a  (u, a complex as f2)
__device__ inline f2 cmad(f2 u, f2 a, f2 acc) {
  const f2 un = {-u.y, u.y};
  return acc + u.x * a + un * fswap(a);
}

template <bool SAFE>
__device__ inline float bcast(float x, int l) {
  if constexpr (SAFE) return __shfl(x, l, 64);
  else return __int_as_float(__builtin_amdgcn_readlane(__float_as_int(x), l));
}

// xor-exchange across lanes — ALL pure VALU on the fast path (no DS pipe):
//   mask 1/2: 1 DPP quad_perm; mask 4: xor7∘xor3 DPP; mask 8: xor15∘xor7 DPP;
//   mask 16/32: permlane swap + 1 cndmask (select precomputed in Ctx).
template <int MASK, bool SAFE>
__device__ inline float xshfl(float x, const Ctx& cx) {
  if constexpr (SAFE) {
    return __shfl_xor(x, MASK, 64);
  } else if constexpr (MASK == 1) {        // quad_perm [1,0,3,2] = xor1
    return __int_as_float(__builtin_amdgcn_update_dpp(0, __float_as_int(x), 0xB1, 0xF, 0xF, true));
  } else if constexpr (MASK == 2) {        // quad_perm [2,3,0,1] = xor2
    return __int_as_float(__builtin_amdgcn_update_dpp(0, __float_as_int(x), 0x4E, 0xF, 0xF, true));
  } else if constexpr (MASK == 4) {        // row_half_mirror (xor7) ∘ quad mirror (xor3)
    int t = __builtin_amdgcn_update_dpp(0, __float_as_int(x), 0x141, 0xF, 0xF, true);
    t = __builtin_amdgcn_update_dpp(0, t, 0x1B, 0xF, 0xF, true);
    return __int_as_float(t);
  } else if constexpr (MASK == 8) {        // row_mirror (xor15) ∘ row_half_mirror (xor7)
    int t = __builtin_amdgcn_update_dpp(0, __float_as_int(x), 0x140, 0xF, 0xF, true);
    t = __builtin_amdgcn_update_dpp(0, t, 0x141, 0xF, 0xF, true);
    return __int_as_float(t);
  } else if constexpr (MASK == 16) {
#if __has_builtin(__builtin_amdgcn_permlane16_swap)
    auto r = __builtin_amdgcn_permlane16_swap(__float_as_int(x), __float_as_int(x), false, false);
    return __int_as_float(cx.s16 ? r[0] : r[1]);
#else
    return __shfl_xor(x, 16, 64);
#endif
  } else {
#if __has_builtin(__builtin_amdgcn_permlane32_swap)
    auto r = __builtin_amdgcn_permlane32_swap(__float_as_int(x), __float_as_int(x), false, false);
    return __int_as_float(cx.s32 ? r[0] : r[1]);
#else
    return __shfl_xor(x, 32, 64);
#endif
  }
}

template <int MASK, bool SAFE>
__device__ inline f2 xshfl2(f2 v, const Ctx& cx) {
  f2 r;
  r.x = xshfl<MASK, SAFE>(v.x, cx);
  r.y = xshfl<MASK, SAFE>(v.y, cx);
  return r;
}

template <int TY, int P>
__device__ inline void gate_local(f2 (&st)[16], float c, float s) {
  const f2 c2 = {c, c}, s2 = {s, s}, sn = {s, -s};
  #pragma unroll
  for (int b = 0; b < 16; ++b) {
    if ((b >> P) & 1) continue;
    const int i0 = b, i1 = b | (1 << P);
    const f2 a0 = st[i0], a1 = st[i1];
    if constexpr (TY == 0) {              // RX
      st[i0] = c2 * a0 + sn * fswap(a1);
      st[i1] = c2 * a1 + sn * fswap(a0);
    } else if constexpr (TY == 1) {       // RY
      st[i0] = c2 * a0 - s2 * a1;
      st[i1] = c2 * a1 + s2 * a0;
    } else {                              // RZ
      st[i0] = c2 * a0 + sn * fswap(a0);
      st[i1] = c2 * a1 - sn * fswap(a1);
    }
  }
}

template <int TY, int LB, bool SAFE>
__device__ inline void gate_lane(f2 (&st)[16], float c, float s, const Ctx& cx) {
  const f2 c2 = {c, c};
  if constexpr (TY == 2) {                // RZ: diagonal, no exchange
    const float t = ((cx.lane >> LB) & 1) ? -s : s;
    const f2 tn = {t, -t};
    #pragma unroll
    for (int j = 0; j < 16; ++j) st[j] = c2 * st[j] + tn * fswap(st[j]);
  } else if constexpr (TY == 0) {         // RX
    const f2 sn = {s, -s};
    #pragma unroll
    for (int j = 0; j < 16; ++j) {
      const f2 p = xshfl2<(1 << LB), SAFE>(st[j], cx);
      st[j] = c2 * st[j] + sn * fswap(p);
    }
  } else {                                // RY
    const float sg = ((cx.lane >> LB) & 1) ? s : -s;
    const f2 sg2 = {sg, sg};
    #pragma unroll
    for (int j = 0; j < 16; ++j) {
      const f2 p = xshfl2<(1 << LB), SAFE>(st[j], cx);
      st[j] = c2 * st[j] + sg2 * p;
    }
  }
}

template <int P>
__device__ inline void fused_local(f2 (&st)[16], const U2v& u) {
  #pragma unroll
  for (int b = 0; b < 16; ++b) {
    if ((b >> P) & 1) continue;
    const int i0 = b, i1 = b | (1 << P);
    const f2 a0 = st[i0], a1 = st[i1];
    st[i0] = cmad(u.u01, a1, cmad(u.u00, a0, (f2){0.f, 0.f}));
    st[i1] = cmad(u.u11, a1, cmad(u.u10, a0, (f2){0.f, 0.f}));
  }
}

template <int LB, bool SAFE>
__device__ inline void fused_lane(f2 (&st)[16], const U2v& u, const Ctx& cx) {
  const bool hi = (cx.lane >> LB) & 1;
  const f2 A = hi ? u.u11 : u.u00;
  const f2 B = hi ? u.u10 : u.u01;
  #pragma unroll
  for (int j = 0; j < 16; ++j) {
    const f2 p = xshfl2<(1 << LB), SAFE>(st[j], cx);
    st[j] = cmad(B, p, cmad(A, st[j], (f2){0.f, 0.f}));
  }
}

template <int CB, int TB, bool SAFE>
__device__ inline void cnot_gate(f2 (&st)[16], const Ctx& cx) {
  if constexpr (CB < 4 && TB < 4) {
    #pragma unroll
    for (int b = 0; b < 16; ++b) {
      if (((b >> CB) & 1) && !((b >> TB) & 1)) {
        const int j = b | (1 << TB);
        const f2 t = st[b]; st[b] = st[j]; st[j] = t;
      }
    }
  } else if constexpr (CB < 4) {
    constexpr int M = 1 << (TB - 4);
    #pragma unroll
    for (int b = 0; b < 16; ++b) {
      if ((b >> CB) & 1) st[b] = xshfl2<M, SAFE>(st[b], cx);
    }
  } else if constexpr (TB < 4) {
    const bool cb = (cx.lane >> (CB - 4)) & 1;
    #pragma unroll
    for (int b = 0; b < 16; ++b) {
      if (!((b >> TB) & 1)) {
        const int j = b | (1 << TB);
        const f2 a0 = st[b], a1 = st[j];
        st[b] = cb ? a1 : a0; st[j] = cb ? a0 : a1;
      }
    }
  } else {
    const bool cb = (cx.lane >> (CB - 4)) & 1;
    constexpr int M = 1 << (TB - 4);
    #pragma unroll
    for (int j = 0; j < 16; ++j) {
      const f2 p = xshfl2<M, SAFE>(st[j], cx);
      st[j] = cb ? p : st[j];
    }
  }
}

template <int K, bool SAFE>
__device__ inline void run_gates(f2 (&st)[16], float tc, float ts, const U2v& u, const Ctx& cx) {
  constexpr int NG = SAFE ? NG_SAFE : NG_FAST;
  if constexpr (K < NG) {
    constexpr int ty = SAFE ? FULLS.type[K] : FULLF.type[K];
    constexpr int P0 = SAFE ? FULLS.p0[K]   : FULLF.p0[K];
    constexpr int P1 = SAFE ? FULLS.p1[K]   : FULLF.p1[K];
    constexpr int AI = SAFE ? FULLS.aidx[K] : FULLF.aidx[K];
    if constexpr (ty == 3) {
      cnot_gate<P0, P1, SAFE>(st, cx);
    } else if constexpr (ty == 4) {
      if constexpr (P0 < 4) fused_local<P0>(st, u);
      else                  fused_lane<P0 - 4, SAFE>(st, u, cx);
    } else {
      const float c = bcast<SAFE>(tc, AI);
      const float s = bcast<SAFE>(ts, AI);
      if constexpr (P0 < 4) gate_local<ty, P0>(st, c, s);
      else                  gate_lane<ty, P0 - 4, SAFE>(st, c, s, cx);
    }
    run_gates<K + 1, SAFE>(st, tc, ts, u, cx);
  }
}

template <bool SAFE>
__device__ inline void body(const Ctx& cx, int b, float tc, float ts,
                            const float* __restrict__ hw, const float* __restrict__ hb,
                            float* __restrict__ out) {
  const int lane = cx.lane;
  U2v u;
  {
    const float cxr = bcast<SAFE>(tc, 40), sxr = bcast<SAFE>(ts, 40);
    const float cyr = bcast<SAFE>(tc, 41), syr = bcast<SAFE>(ts, 41);
    u.u00 = (f2){ cyr * cxr,  syr * sxr};
    u.u01 = (f2){-syr * cxr, -cyr * sxr};
    u.u10 = (f2){ syr * cxr, -cyr * sxr};
    u.u11 = (f2){ cyr * cxr, -syr * sxr};
  }
  float ec[N_WIRES], es[N_WIRES];
  #pragma unroll
  for (int w = 0; w < N_WIRES; ++w) { ec[w] = bcast<SAFE>(tc, w); es[w] = bcast<SAFE>(ts, w); }

  float lp = ((lane >> 0) & 1) ? es[LW0] : ec[LW0];
  lp *= ((lane >> 1) & 1) ? es[LW1] : ec[LW1];
  lp *= ((lane >> 2) & 1) ? es[LW2] : ec[LW2];
  lp *= ((lane >> 3) & 1) ? es[LW3] : ec[LW3];
  lp *= ((lane >> 4) & 1) ? es[LW4] : ec[LW4];
  lp *= ((lane >> 5) & 1) ? es[LW5] : ec[LW5];
  f2 st[16];
  #pragma unroll
  for (int sl = 0; sl < 16; ++sl) {
    float a = lp;
    a *= (sl & 1) ? es[RW0] : ec[RW0];
    a *= (sl & 2) ? es[RW1] : ec[RW1];
    a *= (sl & 4) ? es[RW2] : ec[RW2];
    a *= (sl & 8) ? es[RW3] : ec[RW3];
    st[sl] = (f2){a, 0.0f};
  }

  run_gates<0, SAFE>(st, tc, ts, u, cx);

  float hwv[N_WIRES];
  #pragma unroll
  for (int w = 0; w < N_WIRES; ++w) hwv[w] = hw[w];
  float lw = (((lane >> 0) & 1) ? -hwv[LW0] : hwv[LW0])
           + (((lane >> 1) & 1) ? -hwv[LW1] : hwv[LW1])
           + (((lane >> 2) & 1) ? -hwv[LW2] : hwv[LW2])
           + (((lane >> 3) & 1) ? -hwv[LW3] : hwv[LW3])
           + (((lane >> 4) & 1) ? -hwv[LW4] : hwv[LW4])
           + (((lane >> 5) & 1) ? -hwv[LW5] : hwv[LW5]);
  float acc = 0.0f;
  #pragma unroll
  for (int sl = 0; sl < 16; ++sl) {
    float sw = lw;
    sw += (sl & 1) ? -hwv[RW0] : hwv[RW0];
    sw += (sl & 2) ? -hwv[RW1] : hwv[RW1];
    sw += (sl & 4) ? -hwv[RW2] : hwv[RW2];
    sw += (sl & 8) ? -hwv[RW3] : hwv[RW3];
    const f2 q = st[sl] * st[sl];
    acc += (q.x + q.y) * sw;
  }
  acc += xshfl<1,  SAFE>(acc, cx);
  acc += xshfl<2,  SAFE>(acc, cx);
  acc += xshfl<4,  SAFE>(acc, cx);
  acc += xshfl<8,  SAFE>(acc, cx);
  acc += xshfl<16, SAFE>(acc, cx);
  acc += xshfl<32, SAFE>(acc, cx);
  if (lane == 0) {
    const float logit = acc + hb[0] + 1.57079632679489662f;  // + SHIFT
    out[b] = 1.0f / (1.0f + expf(-logit));
  }
}

__global__ __launch_bounds__(256)
void qsim_kernel(const float* __restrict__ xb, const float* __restrict__ rxt,
                 const float* __restrict__ ryt, const float* __restrict__ rp,
                 const float* __restrict__ hw, const float* __restrict__ hb,
                 float* __restrict__ out, int bsz) {
  const int lane = threadIdx.x & 63;
  const int b = blockIdx.x * 4 + (threadIdx.x >> 6);  // one wave = one sample
  if (b >= bsz) return;

  float tc, ts;
  {
    float t = 0.0f;
    if (lane < 10)        t = xb[(size_t)b * 10 + lane];
    else if (lane < 40)   t = rp[lane - 10];
    else if (lane == 40)  t = rxt[0];
    else if (lane == 41)  t = ryt[0];
    float s, c;
    sincosf(0.5f * t, &s, &c);
    tc = c; ts = s;
  }

  // ---- mechanism self-test: orientation probes + end-to-end validation ----
  Ctx cx; cx.lane = lane; cx.s16 = false; cx.s32 = false;
#if __has_builtin(__builtin_amdgcn_permlane16_swap)
  {
    auto r = __builtin_amdgcn_permlane16_swap(lane, lane, false, false);
    const bool f16 = (((lane & 16) ? r[0] : r[1]) != (lane ^ 16));
    cx.s16 = (((lane & 16) != 0) ^ f16);
  }
#endif
#if __has_builtin(__builtin_amdgcn_permlane32_swap)
  {
    auto r = __builtin_amdgcn_permlane32_swap(lane, lane, false, false);
    const bool f32 = (((lane & 32) ? r[0] : r[1]) != (lane ^ 32));
    cx.s32 = (((lane & 32) != 0) ^ f32);
  }
#endif
  bool ok = true;
  ok &= (__float_as_int(xshfl<1,  false>(__int_as_float(lane), cx)) == (lane ^ 1));
  ok &= (__float_as_int(xshfl<2,  false>(__int_as_float(lane), cx)) == (lane ^ 2));
  ok &= (__float_as_int(xshfl<4,  false>(__int_as_float(lane), cx)) == (lane ^ 4));
  ok &= (__float_as_int(xshfl<8,  false>(__int_as_float(lane), cx)) == (lane ^ 8));
  ok &= (__float_as_int(xshfl<16, false>(__int_as_float(lane), cx)) == (lane ^ 16));
  ok &= (__float_as_int(xshfl<32, false>(__int_as_float(lane), cx)) == (lane ^ 32));
  const bool fast = (__all((int)ok) != 0);

  if (fast) body<false>(cx, b, tc, ts, hw, hb, out);
  else      body<true >(cx, b, tc, ts, hw, hb, out);
}

// ---------------------------------- launch -----------------------------------

extern "C" void kernel_launch(void* const* d_in, const int* in_sizes, int n_in,
                              void* d_out, int out_size, void* d_ws, size_t ws_size,
                              hipStream_t stream) {
  const float* xb  = (const float*)d_in[0];
  const float* rxt = (const float*)d_in[1];
  const float* ryt = (const float*)d_in[2];
  const float* rp  = (const float*)d_in[3];
  const float* hw  = (const float*)d_in[4];
  const float* hb  = (const float*)d_in[5];
  float* out = (float*)d_out;

  const int bsz = in_sizes[0] / N_WIRES;
  const int nblk = (bsz + 3) / 4;

  hipLaunchKernelGGL(qsim_kernel, dim3(nblk), dim3(256), 0, stream,
                     xb, rxt, ryt, rp, hw, hb, out, bsz);
}